// Round 1
// baseline (972.256 us; speedup 1.0000x reference)
//
#include <hip/hip_runtime.h>

#define Bb 2
#define Tt 4096
#define Dd 1024
#define Hh 16
#define QKd 64
#define VDd 64
#define BT (Bb*Tt)          // 8192
#define NCH 16
#define CHUNK (Tt/NCH)      // 256

// workspace layout (floats)
#define OFF_QF  0
#define OFF_KF  (OFF_QF + (size_t)BT*Dd)
#define OFF_V   (OFF_KF + (size_t)BT*Dd)
#define OFF_KVP (OFF_V + (size_t)BT*Dd)          // kv partials: NCH*32*4096
#define OFF_KSP (OFF_KVP + (size_t)NCH*32*4096)  // ksum partials: NCH*32*64
#define OFF_KV  (OFF_KSP + (size_t)NCH*32*64)    // 32*4096
#define OFF_KS  (OFF_KV + (size_t)32*4096)       // 32*64
#define OFF_KVQ (OFF_KS + (size_t)32*64)         // folded kv@Wproj^T: 32*64*1024
#define OFF_Z   (OFF_KVQ + (size_t)32*64*1024)   // BT*Hh

__device__ __forceinline__ float featmap(float x) {
    // elu(x)+1 = x+1 (x>0) else exp(x)
    return x > 0.f ? x + 1.f : __expf(x);
}

// C[M,N] = A[M,K] @ W[N,K]^T, optional elu+1 epilogue.
// 128x128 tile, 256 threads, 8x8 per thread as 2x2 of 4x4 (conflict-free b128 LDS reads)
template<int ELU>
__global__ __launch_bounds__(256) void gemm_xw(const float* __restrict__ A,
                                               const float* __restrict__ W,
                                               float* __restrict__ C,
                                               int M, int N, int K)
{
    __shared__ float As[16][132];
    __shared__ float Bs[16][132];
    const int tid = threadIdx.x;
    const int n0 = blockIdx.x * 128;
    const int m0 = blockIdx.y * 128;
    const int tx = tid & 15;
    const int ty = tid >> 4;
    const int lr = tid >> 2;
    const int k4 = (tid & 3) << 2;
    float acc[2][2][4][4] = {};

    for (int k0 = 0; k0 < K; k0 += 16) {
        float4 a0 = *(const float4*)&A[(size_t)(m0 + lr) * K + k0 + k4];
        float4 a1 = *(const float4*)&A[(size_t)(m0 + 64 + lr) * K + k0 + k4];
        float4 b0 = *(const float4*)&W[(size_t)(n0 + lr) * K + k0 + k4];
        float4 b1 = *(const float4*)&W[(size_t)(n0 + 64 + lr) * K + k0 + k4];
        __syncthreads();
        As[k4+0][lr] = a0.x; As[k4+1][lr] = a0.y; As[k4+2][lr] = a0.z; As[k4+3][lr] = a0.w;
        As[k4+0][64+lr] = a1.x; As[k4+1][64+lr] = a1.y; As[k4+2][64+lr] = a1.z; As[k4+3][64+lr] = a1.w;
        Bs[k4+0][lr] = b0.x; Bs[k4+1][lr] = b0.y; Bs[k4+2][lr] = b0.z; Bs[k4+3][lr] = b0.w;
        Bs[k4+0][64+lr] = b1.x; Bs[k4+1][64+lr] = b1.y; Bs[k4+2][64+lr] = b1.z; Bs[k4+3][64+lr] = b1.w;
        __syncthreads();
        #pragma unroll
        for (int kk = 0; kk < 16; ++kk) {
            float4 alo = *(const float4*)&As[kk][ty*4];
            float4 ahi = *(const float4*)&As[kk][64+ty*4];
            float4 blo = *(const float4*)&Bs[kk][tx*4];
            float4 bhi = *(const float4*)&Bs[kk][64+tx*4];
            float av[2][4] = {{alo.x,alo.y,alo.z,alo.w},{ahi.x,ahi.y,ahi.z,ahi.w}};
            float bv[2][4] = {{blo.x,blo.y,blo.z,blo.w},{bhi.x,bhi.y,bhi.z,bhi.w}};
            #pragma unroll
            for (int rh = 0; rh < 2; ++rh)
                #pragma unroll
                for (int i = 0; i < 4; ++i)
                    #pragma unroll
                    for (int chh = 0; chh < 2; ++chh)
                        #pragma unroll
                        for (int j = 0; j < 4; ++j)
                            acc[rh][chh][i][j] = fmaf(av[rh][i], bv[chh][j], acc[rh][chh][i][j]);
        }
    }
    #pragma unroll
    for (int rh = 0; rh < 2; ++rh)
        #pragma unroll
        for (int i = 0; i < 4; ++i) {
            int row = m0 + rh*64 + ty*4 + i;
            #pragma unroll
            for (int chh = 0; chh < 2; ++chh) {
                float4 o;
                if (ELU) {
                    o.x = featmap(acc[rh][chh][i][0]);
                    o.y = featmap(acc[rh][chh][i][1]);
                    o.z = featmap(acc[rh][chh][i][2]);
                    o.w = featmap(acc[rh][chh][i][3]);
                } else {
                    o.x = acc[rh][chh][i][0];
                    o.y = acc[rh][chh][i][1];
                    o.z = acc[rh][chh][i][2];
                    o.w = acc[rh][chh][i][3];
                }
                *(float4*)&C[(size_t)row * N + n0 + chh*64 + tx*4] = o;
            }
        }
}

// per (b,h), T-chunk: partial kv[64][64] and ksum[64]
__global__ __launch_bounds__(256) void kv_partial(const float* __restrict__ kf,
        const float* __restrict__ vf, float* __restrict__ kvpart, float* __restrict__ kspart)
{
    const int bh = blockIdx.x;       // b*16+h
    const int ch = blockIdx.y;
    const int b = bh >> 4, h = bh & 15;
    __shared__ float sk[8][64];
    __shared__ float sv[8][64];
    const int tid = threadIdx.x;
    const int r0 = (tid >> 4) << 2;  // 0..60
    const int c0 = (tid & 15) << 2;  // 0..60
    const int tt = tid >> 5;         // 0..7
    const int rem = tid & 31;
    const int which = rem >> 4;      // 0:k 1:v
    const int d4 = (rem & 15) << 2;
    const float* src = which ? vf : kf;
    float acc[4][4] = {};
    float ksl = 0.f;
    for (int t0 = ch * CHUNK; t0 < (ch + 1) * CHUNK; t0 += 8) {
        const int t = t0 + tt;
        float4 val = *(const float4*)&src[(size_t)(b*Tt + t)*Dd + h*QKd + d4];
        __syncthreads();
        if (which) *(float4*)&sv[tt][d4] = val;
        else       *(float4*)&sk[tt][d4] = val;
        __syncthreads();
        #pragma unroll
        for (int s = 0; s < 8; ++s) {
            float4 k4v = *(const float4*)&sk[s][r0];
            float4 v4v = *(const float4*)&sv[s][c0];
            float kvv[4] = {k4v.x,k4v.y,k4v.z,k4v.w};
            float vvv[4] = {v4v.x,v4v.y,v4v.z,v4v.w};
            #pragma unroll
            for (int i = 0; i < 4; ++i)
                #pragma unroll
                for (int j = 0; j < 4; ++j)
                    acc[i][j] = fmaf(kvv[i], vvv[j], acc[i][j]);
        }
        if (tid < 64) {
            #pragma unroll
            for (int s = 0; s < 8; ++s) ksl += sk[s][tid];
        }
    }
    const size_t base = (size_t)(ch*32 + bh) * 4096;
    #pragma unroll
    for (int i = 0; i < 4; ++i) {
        float4 o = {acc[i][0], acc[i][1], acc[i][2], acc[i][3]};
        *(float4*)&kvpart[base + (r0+i)*64 + c0] = o;
    }
    if (tid < 64) kspart[(size_t)(ch*32 + bh)*64 + tid] = ksl;
}

__global__ __launch_bounds__(256) void kv_reduce(const float* __restrict__ kvpart,
        const float* __restrict__ kspart, float* __restrict__ kv, float* __restrict__ ksum)
{
    int g = blockIdx.x * 256 + threadIdx.x;
    if (g < 32*4096) {
        float s = 0.f;
        #pragma unroll
        for (int c = 0; c < NCH; ++c) s += kvpart[(size_t)c*(32*4096) + g];
        kv[g] = s;
    } else if (g < 32*4096 + 32*64) {
        int g2 = g - 32*4096;
        float s = 0.f;
        #pragma unroll
        for (int c = 0; c < NCH; ++c) s += kspart[(size_t)c*(32*64) + g2];
        ksum[g2] = s;
    }
}

// kvq[bh][d][c] = sum_m kv[bh][d][m] * Wproj[c][m]
__global__ __launch_bounds__(256) void kvp_kernel(const float* __restrict__ kv,
        const float* __restrict__ wproj, float* __restrict__ kvq)
{
    int flat = blockIdx.x * 256 + threadIdx.x;   // < 32*64*1024
    int bh = flat >> 16;
    int rem = flat & 65535;
    int d = rem >> 10;
    int c = rem & 1023;
    const float4* kr = (const float4*)&kv[(size_t)(bh*64 + d)*64];
    const float4* wr = (const float4*)&wproj[(size_t)c*64];
    float s = 0.f;
    #pragma unroll
    for (int m = 0; m < 16; ++m) {
        float4 a = kr[m], bq = wr[m];
        s += a.x*bq.x + a.y*bq.y + a.z*bq.z + a.w*bq.w;
    }
    kvq[flat] = s;
}

// z[bt*16+h] = 1 / dot(q[bt,h,:], ksum[b,h,:])
__global__ __launch_bounds__(256) void z_kernel(const float* __restrict__ qf,
        const float* __restrict__ ksum, float* __restrict__ z)
{
    int r = blockIdx.x * 256 + threadIdx.x;  // < BT*Hh
    int bt = r >> 4, h = r & 15;
    int b = bt >> 12;
    const float4* qr = (const float4*)&qf[(size_t)bt*Dd + h*64];
    const float4* kr = (const float4*)&ksum[(size_t)(b*16 + h)*64];
    float s = 0.f;
    #pragma unroll
    for (int m = 0; m < 16; ++m) {
        float4 a = qr[m], bq = kr[m];
        s += a.x*bq.x + a.y*bq.y + a.z*bq.z + a.w*bq.w;
    }
    z[r] = 1.f / s;
}

// out[b,t,h,c] = z[b,t,h] * sum_d q[b,t,h,d] * kvq[bh][d][c]
__global__ __launch_bounds__(256) void final_gemm(const float* __restrict__ qf,
        const float* __restrict__ kvq, const float* __restrict__ z, float* __restrict__ out)
{
    const int bh = blockIdx.z;
    const int b = bh >> 4, h = bh & 15;
    const int t0 = blockIdx.y * 128;
    const int c0 = blockIdx.x * 128;
    __shared__ float As[16][132];
    __shared__ float Bs[16][132];
    __shared__ float zs[128];
    const int tid = threadIdx.x;
    const int tx = tid & 15, ty = tid >> 4;
    const int lr = tid >> 2, k4 = (tid & 3) << 2;
    float acc[2][2][4][4] = {};
    if (tid < 128) zs[tid] = z[(size_t)(b*Tt + t0 + tid)*Hh + h];

    for (int k0 = 0; k0 < 64; k0 += 16) {
        float4 a0 = *(const float4*)&qf[(size_t)(b*Tt + t0 + lr)*Dd + h*QKd + k0 + k4];
        float4 a1 = *(const float4*)&qf[(size_t)(b*Tt + t0 + 64 + lr)*Dd + h*QKd + k0 + k4];
        const int kk0 = tid >> 5, cc0 = (tid & 31) << 2;
        const int kk1 = 8 + (tid >> 5), cc1 = cc0;
        float4 b0v = *(const float4*)&kvq[(size_t)(bh*64 + k0 + kk0)*1024 + c0 + cc0];
        float4 b1v = *(const float4*)&kvq[(size_t)(bh*64 + k0 + kk1)*1024 + c0 + cc1];
        __syncthreads();
        As[k4+0][lr] = a0.x; As[k4+1][lr] = a0.y; As[k4+2][lr] = a0.z; As[k4+3][lr] = a0.w;
        As[k4+0][64+lr] = a1.x; As[k4+1][64+lr] = a1.y; As[k4+2][64+lr] = a1.z; As[k4+3][64+lr] = a1.w;
        *(float4*)&Bs[kk0][cc0] = b0v;
        *(float4*)&Bs[kk1][cc1] = b1v;
        __syncthreads();
        #pragma unroll
        for (int kk = 0; kk < 16; ++kk) {
            float4 alo = *(const float4*)&As[kk][ty*4];
            float4 ahi = *(const float4*)&As[kk][64+ty*4];
            float4 blo = *(const float4*)&Bs[kk][tx*4];
            float4 bhi = *(const float4*)&Bs[kk][64+tx*4];
            float av[2][4] = {{alo.x,alo.y,alo.z,alo.w},{ahi.x,ahi.y,ahi.z,ahi.w}};
            float bv[2][4] = {{blo.x,blo.y,blo.z,blo.w},{bhi.x,bhi.y,bhi.z,bhi.w}};
            #pragma unroll
            for (int rh = 0; rh < 2; ++rh)
                #pragma unroll
                for (int i = 0; i < 4; ++i)
                    #pragma unroll
                    for (int chh = 0; chh < 2; ++chh)
                        #pragma unroll
                        for (int j = 0; j < 4; ++j)
                            acc[rh][chh][i][j] = fmaf(av[rh][i], bv[chh][j], acc[rh][chh][i][j]);
        }
    }
    #pragma unroll
    for (int rh = 0; rh < 2; ++rh)
        #pragma unroll
        for (int i = 0; i < 4; ++i) {
            int row = rh*64 + ty*4 + i;
            float zv = zs[row];
            #pragma unroll
            for (int chh = 0; chh < 2; ++chh) {
                float4 o;
                o.x = acc[rh][chh][i][0] * zv;
                o.y = acc[rh][chh][i][1] * zv;
                o.z = acc[rh][chh][i][2] * zv;
                o.w = acc[rh][chh][i][3] * zv;
                *(float4*)&out[((size_t)(b*Tt + t0 + row)*Hh + h)*Dd + c0 + chh*64 + tx*4] = o;
            }
        }
}

extern "C" void kernel_launch(void* const* d_in, const int* in_sizes, int n_in,
                              void* d_out, int out_size, void* d_ws, size_t ws_size,
                              hipStream_t stream)
{
    const float* x  = (const float*)d_in[0];
    const float* WQ = (const float*)d_in[1];
    const float* WK = (const float*)d_in[2];
    const float* WV = (const float*)d_in[3];
    const float* Wp = (const float*)d_in[4];
    float* ws = (float*)d_ws;
    float* qf     = ws + OFF_QF;
    float* kf     = ws + OFF_KF;
    float* vf     = ws + OFF_V;
    float* kvpart = ws + OFF_KVP;
    float* kspart = ws + OFF_KSP;
    float* kv     = ws + OFF_KV;
    float* ksum   = ws + OFF_KS;
    float* kvq    = ws + OFF_KVQ;
    float* zz     = ws + OFF_Z;
    float* out = (float*)d_out;

    dim3 blk(256);
    // QKV projections (feature map fused for Q,K)
    gemm_xw<1><<<dim3(8, 64), blk, 0, stream>>>(x, WQ, qf, BT, Dd, Dd);
    gemm_xw<1><<<dim3(8, 64), blk, 0, stream>>>(x, WK, kf, BT, Dd, Dd);
    gemm_xw<0><<<dim3(8, 64), blk, 0, stream>>>(x, WV, vf, BT, Dd, Dd);
    // kv & ksum reduction over T
    kv_partial<<<dim3(32, NCH), blk, 0, stream>>>(kf, vf, kvpart, kspart);
    kv_reduce<<<(32*4096 + 32*64 + 255)/256, blk, 0, stream>>>(kvpart, kspart, kv, ksum);
    // fold output projection into kv
    kvp_kernel<<<(32*64*1024)/256, blk, 0, stream>>>(kv, Wp, kvq);
    // normalizer
    z_kernel<<<(BT*Hh)/256, blk, 0, stream>>>(qf, ksum, zz);
    // final: out = z * (q @ kvq)
    final_gemm<<<dim3(8, 32, 32), blk, 0, stream>>>(qf, kvq, zz, out);
}

// Round 2
// 631.170 us; speedup vs baseline: 1.5404x; 1.5404x over previous
//
#include <hip/hip_runtime.h>

#define Bb 2
#define Tt 4096
#define Dd 1024
#define Hh 16
#define QKd 64
#define VDd 64
#define BT (Bb*Tt)          // 8192
#define NCH 16
#define CHUNK (Tt/NCH)      // 256

// workspace layout (float units)
#define OFF_QF  0
#define OFF_KF  (OFF_QF + (size_t)BT*Dd)
#define OFF_V   (OFF_KF + (size_t)BT*Dd)
#define OFF_KVP (OFF_V + (size_t)BT*Dd)          // kv partials: NCH*32*4096
#define OFF_KSP (OFF_KVP + (size_t)NCH*32*4096)  // ksum partials: NCH*32*64
#define OFF_KV  (OFF_KSP + (size_t)NCH*32*64)    // 32*4096
#define OFF_KS  (OFF_KV + (size_t)32*4096)       // 32*64
#define OFF_KVQ (OFF_KS + (size_t)32*64)         // folded kv@Wproj^T: 32*64*1024
#define OFF_Z   (OFF_KVQ + (size_t)32*64*1024)   // BT*Hh
#define OFF_AB  (OFF_Z + (size_t)BT*Hh)                 // Abig: BT x 2048 ushort (hi|lo)
#define OFF_WQB (OFF_AB + (size_t)BT*2048/2)            // Wbig: 1024 x 3072 ushort (hi|lo|hi)
#define OFF_WKB (OFF_WQB + (size_t)1024*3072/2)
#define OFF_WVB (OFF_WKB + (size_t)1024*3072/2)

typedef __attribute__((ext_vector_type(8))) short short8;
typedef __attribute__((ext_vector_type(4))) float f32x4;

__device__ __forceinline__ float featmap(float x) {
    // elu(x)+1 = x+1 (x>0) else exp(x)
    return x > 0.f ? x + 1.f : __expf(x);
}

__device__ __forceinline__ unsigned short bf16_rne(float f) {
    unsigned int u = __float_as_uint(f);
    unsigned int r = u + 0x7fffu + ((u >> 16) & 1u);
    return (unsigned short)(r >> 16);
}
__device__ __forceinline__ float bf16_to_f(unsigned short h) {
    return __uint_as_float(((unsigned int)h) << 16);
}

// split x[8192][1024] f32 -> Abig[8192][2048] bf16: cols [0,1024)=hi, [1024,2048)=lo
__global__ __launch_bounds__(256) void split_a(const float* __restrict__ src,
                                               unsigned short* __restrict__ dst)
{
    int idx = blockIdx.x * 256 + threadIdx.x;   // over BT*1024/4 float4s
    int m = idx >> 8;
    int c = (idx & 255) << 2;
    float4 v = *(const float4*)&src[(size_t)m * 1024 + c];
    ushort4 hi, lo;
    hi.x = bf16_rne(v.x); lo.x = bf16_rne(v.x - bf16_to_f(hi.x));
    hi.y = bf16_rne(v.y); lo.y = bf16_rne(v.y - bf16_to_f(hi.y));
    hi.z = bf16_rne(v.z); lo.z = bf16_rne(v.z - bf16_to_f(hi.z));
    hi.w = bf16_rne(v.w); lo.w = bf16_rne(v.w - bf16_to_f(hi.w));
    *(ushort4*)&dst[(size_t)m * 2048 + c] = hi;
    *(ushort4*)&dst[(size_t)m * 2048 + 1024 + c] = lo;
}

// split W[1024][1024] f32 -> Wbig[1024][3072] bf16: [0,1024)=hi, [1024,2048)=lo, [2048,3072)=hi
__global__ __launch_bounds__(256) void split_w(const float* __restrict__ src,
                                               unsigned short* __restrict__ dst)
{
    int idx = blockIdx.x * 256 + threadIdx.x;   // over 1024*1024/4
    int m = idx >> 8;
    int c = (idx & 255) << 2;
    float4 v = *(const float4*)&src[(size_t)m * 1024 + c];
    ushort4 hi, lo;
    hi.x = bf16_rne(v.x); lo.x = bf16_rne(v.x - bf16_to_f(hi.x));
    hi.y = bf16_rne(v.y); lo.y = bf16_rne(v.y - bf16_to_f(hi.y));
    hi.z = bf16_rne(v.z); lo.z = bf16_rne(v.z - bf16_to_f(hi.z));
    hi.w = bf16_rne(v.w); lo.w = bf16_rne(v.w - bf16_to_f(hi.w));
    *(ushort4*)&dst[(size_t)m * 3072 + c] = hi;
    *(ushort4*)&dst[(size_t)m * 3072 + 1024 + c] = lo;
    *(ushort4*)&dst[(size_t)m * 3072 + 2048 + c] = hi;
}

#define GLLDS(gp, lp) __builtin_amdgcn_global_load_lds( \
    (const __attribute__((address_space(1))) void*)(gp), \
    (__attribute__((address_space(3))) void*)(lp), 16, 0, 0)

// C[M][1024] f32 = Abig[M][2048](hi|lo) x Wbig[1024][3072](hi|lo|hi)^T over effective K=3072
// (computes hi*hi + hi*lo + lo*hi == fp32-accurate product). m97-style MFMA structure:
// 128x128 tile, 4 waves (each 64x64 = 4x4 frags of 16x16x32), global_load_lds(16B), LDS dbuf.
template<int ELU>
__global__ __launch_bounds__(256) void gemm_mfma(const unsigned short* __restrict__ A,
                                                 const unsigned short* __restrict__ W,
                                                 float* __restrict__ C)
{
    __shared__ unsigned short Als[2][128*32];
    __shared__ unsigned short Bls[2][128*32];
    const int tid  = threadIdx.x;
    const int lane = tid & 63;
    const int wave = tid >> 6;
    const int n0 = blockIdx.x * 128;
    const int m0 = blockIdx.y * 128;
    const int wr = (wave >> 1) * 64;
    const int wc = (wave & 1) * 64;
    f32x4 acc[4][4] = {};

    auto stage = [&](int buf, int kt) {
        const int k0 = kt * 32;
        const int pass = k0 >> 10;
        const int acol = (pass == 2) ? (k0 - 1024) : (k0 & 1023); // hi,hi,lo passes
        #pragma unroll
        for (int i = 0; i < 2; ++i) {
            int s = i * 256 + tid;          // 512 slots of 16B per tile
            int row = s >> 2, g = s & 3;    // g = 8-elem k-group
            GLLDS(&A[(size_t)(m0 + row) * 2048 + acol + g * 8], &Als[buf][s * 8]);
            GLLDS(&W[(size_t)(n0 + row) * 3072 + k0   + g * 8], &Bls[buf][s * 8]);
        }
    };

    stage(0, 0);
    const int arow = (lane & 15) * 32 + (lane >> 4) * 8;
    for (int kt = 0; kt < 96; ++kt) {
        const int buf = kt & 1;
        __syncthreads();                       // drains vmcnt for buf
        if (kt + 1 < 96) stage(buf ^ 1, kt + 1);
        short8 af[4], bfr[4];
        #pragma unroll
        for (int m = 0; m < 4; ++m)
            af[m] = *(const short8*)&Als[buf][(wr + m*16)*32 + arow];
        #pragma unroll
        for (int n = 0; n < 4; ++n)
            bfr[n] = *(const short8*)&Bls[buf][(wc + n*16)*32 + arow];
        #pragma unroll
        for (int m = 0; m < 4; ++m)
            #pragma unroll
            for (int n = 0; n < 4; ++n)
                acc[m][n] = __builtin_amdgcn_mfma_f32_16x16x32_bf16(af[m], bfr[n], acc[m][n], 0, 0, 0);
    }

    #pragma unroll
    for (int m = 0; m < 4; ++m) {
        #pragma unroll
        for (int n = 0; n < 4; ++n) {
            #pragma unroll
            for (int r = 0; r < 4; ++r) {
                float v = acc[m][n][r];
                if (ELU) v = featmap(v);
                int row = m0 + wr + m*16 + ((lane >> 4) << 2) + r;
                int col = n0 + wc + n*16 + (lane & 15);
                C[(size_t)row * 1024 + col] = v;
            }
        }
    }
}

// per (b,h), T-chunk: partial kv[64][64] and ksum[64]
__global__ __launch_bounds__(256) void kv_partial(const float* __restrict__ kf,
        const float* __restrict__ vf, float* __restrict__ kvpart, float* __restrict__ kspart)
{
    const int bh = blockIdx.x;       // b*16+h
    const int ch = blockIdx.y;
    const int b = bh >> 4, h = bh & 15;
    __shared__ float sk[8][64];
    __shared__ float sv[8][64];
    const int tid = threadIdx.x;
    const int r0 = (tid >> 4) << 2;
    const int c0 = (tid & 15) << 2;
    const int tt = tid >> 5;
    const int rem = tid & 31;
    const int which = rem >> 4;
    const int d4 = (rem & 15) << 2;
    const float* src = which ? vf : kf;
    float acc[4][4] = {};
    float ksl = 0.f;
    for (int t0 = ch * CHUNK; t0 < (ch + 1) * CHUNK; t0 += 8) {
        const int t = t0 + tt;
        float4 val = *(const float4*)&src[(size_t)(b*Tt + t)*Dd + h*QKd + d4];
        __syncthreads();
        if (which) *(float4*)&sv[tt][d4] = val;
        else       *(float4*)&sk[tt][d4] = val;
        __syncthreads();
        #pragma unroll
        for (int s = 0; s < 8; ++s) {
            float4 k4v = *(const float4*)&sk[s][r0];
            float4 v4v = *(const float4*)&sv[s][c0];
            float kvv[4] = {k4v.x,k4v.y,k4v.z,k4v.w};
            float vvv[4] = {v4v.x,v4v.y,v4v.z,v4v.w};
            #pragma unroll
            for (int i = 0; i < 4; ++i)
                #pragma unroll
                for (int j = 0; j < 4; ++j)
                    acc[i][j] = fmaf(kvv[i], vvv[j], acc[i][j]);
        }
        if (tid < 64) {
            #pragma unroll
            for (int s = 0; s < 8; ++s) ksl += sk[s][tid];
        }
    }
    const size_t base = (size_t)(ch*32 + bh) * 4096;
    #pragma unroll
    for (int i = 0; i < 4; ++i) {
        float4 o = {acc[i][0], acc[i][1], acc[i][2], acc[i][3]};
        *(float4*)&kvpart[base + (r0+i)*64 + c0] = o;
    }
    if (tid < 64) kspart[(size_t)(ch*32 + bh)*64 + tid] = ksl;
}

__global__ __launch_bounds__(256) void kv_reduce(const float* __restrict__ kvpart,
        const float* __restrict__ kspart, float* __restrict__ kv, float* __restrict__ ksum)
{
    int g = blockIdx.x * 256 + threadIdx.x;
    if (g < 32*4096) {
        float s = 0.f;
        #pragma unroll
        for (int c = 0; c < NCH; ++c) s += kvpart[(size_t)c*(32*4096) + g];
        kv[g] = s;
    } else if (g < 32*4096 + 32*64) {
        int g2 = g - 32*4096;
        float s = 0.f;
        #pragma unroll
        for (int c = 0; c < NCH; ++c) s += kspart[(size_t)c*(32*64) + g2];
        ksum[g2] = s;
    }
}

// kvq[bh][d][c] = sum_m kv[bh][d][m] * Wproj[c][m]
__global__ __launch_bounds__(256) void kvp_kernel(const float* __restrict__ kv,
        const float* __restrict__ wproj, float* __restrict__ kvq)
{
    int flat = blockIdx.x * 256 + threadIdx.x;   // < 32*64*1024
    int bh = flat >> 16;
    int rem = flat & 65535;
    int d = rem >> 10;
    int c = rem & 1023;
    const float4* kr = (const float4*)&kv[(size_t)(bh*64 + d)*64];
    const float4* wr = (const float4*)&wproj[(size_t)c*64];
    float s = 0.f;
    #pragma unroll
    for (int m = 0; m < 16; ++m) {
        float4 a = kr[m], bq = wr[m];
        s += a.x*bq.x + a.y*bq.y + a.z*bq.z + a.w*bq.w;
    }
    kvq[flat] = s;
}

// z[bt*16+h] = 1 / dot(q[bt,h,:], ksum[b,h,:])
__global__ __launch_bounds__(256) void z_kernel(const float* __restrict__ qf,
        const float* __restrict__ ksum, float* __restrict__ z)
{
    int r = blockIdx.x * 256 + threadIdx.x;  // < BT*Hh
    int bt = r >> 4, h = r & 15;
    int b = bt >> 12;
    const float4* qr = (const float4*)&qf[(size_t)bt*Dd + h*64];
    const float4* kr = (const float4*)&ksum[(size_t)(b*16 + h)*64];
    float s = 0.f;
    #pragma unroll
    for (int m = 0; m < 16; ++m) {
        float4 a = qr[m], bq = kr[m];
        s += a.x*bq.x + a.y*bq.y + a.z*bq.z + a.w*bq.w;
    }
    z[r] = 1.f / s;
}

// out[b,t,h,c] = z[b,t,h] * sum_d q[b,t,h,d] * kvq[bh][d][c]
__global__ __launch_bounds__(256) void final_gemm(const float* __restrict__ qf,
        const float* __restrict__ kvq, const float* __restrict__ z, float* __restrict__ out)
{
    const int bh = blockIdx.z;
    const int b = bh >> 4, h = bh & 15;
    const int t0 = blockIdx.y * 128;
    const int c0 = blockIdx.x * 128;
    __shared__ float As[16][132];
    __shared__ float Bs[16][132];
    __shared__ float zs[128];
    const int tid = threadIdx.x;
    const int tx = tid & 15, ty = tid >> 4;
    const int lr = tid >> 2, k4 = (tid & 3) << 2;
    float acc[2][2][4][4] = {};
    if (tid < 128) zs[tid] = z[(size_t)(b*Tt + t0 + tid)*Hh + h];

    for (int k0 = 0; k0 < 64; k0 += 16) {
        float4 a0 = *(const float4*)&qf[(size_t)(b*Tt + t0 + lr)*Dd + h*QKd + k0 + k4];
        float4 a1 = *(const float4*)&qf[(size_t)(b*Tt + t0 + 64 + lr)*Dd + h*QKd + k0 + k4];
        const int kk0 = tid >> 5, cc0 = (tid & 31) << 2;
        const int kk1 = 8 + (tid >> 5), cc1 = cc0;
        float4 b0v = *(const float4*)&kvq[(size_t)(bh*64 + k0 + kk0)*1024 + c0 + cc0];
        float4 b1v = *(const float4*)&kvq[(size_t)(bh*64 + k0 + kk1)*1024 + c0 + cc1];
        __syncthreads();
        As[k4+0][lr] = a0.x; As[k4+1][lr] = a0.y; As[k4+2][lr] = a0.z; As[k4+3][lr] = a0.w;
        As[k4+0][64+lr] = a1.x; As[k4+1][64+lr] = a1.y; As[k4+2][64+lr] = a1.z; As[k4+3][64+lr] = a1.w;
        *(float4*)&Bs[kk0][cc0] = b0v;
        *(float4*)&Bs[kk1][cc1] = b1v;
        __syncthreads();
        #pragma unroll
        for (int kk = 0; kk < 16; ++kk) {
            float4 alo = *(const float4*)&As[kk][ty*4];
            float4 ahi = *(const float4*)&As[kk][64+ty*4];
            float4 blo = *(const float4*)&Bs[kk][tx*4];
            float4 bhi = *(const float4*)&Bs[kk][64+tx*4];
            float av[2][4] = {{alo.x,alo.y,alo.z,alo.w},{ahi.x,ahi.y,ahi.z,ahi.w}};
            float bv[2][4] = {{blo.x,blo.y,blo.z,blo.w},{bhi.x,bhi.y,bhi.z,bhi.w}};
            #pragma unroll
            for (int rh = 0; rh < 2; ++rh)
                #pragma unroll
                for (int i = 0; i < 4; ++i)
                    #pragma unroll
                    for (int chh = 0; chh < 2; ++chh)
                        #pragma unroll
                        for (int j = 0; j < 4; ++j)
                            acc[rh][chh][i][j] = fmaf(av[rh][i], bv[chh][j], acc[rh][chh][i][j]);
        }
    }
    #pragma unroll
    for (int rh = 0; rh < 2; ++rh)
        #pragma unroll
        for (int i = 0; i < 4; ++i) {
            int row = rh*64 + ty*4 + i;
            float zv = zs[row];
            #pragma unroll
            for (int chh = 0; chh < 2; ++chh) {
                float4 o;
                o.x = acc[rh][chh][i][0] * zv;
                o.y = acc[rh][chh][i][1] * zv;
                o.z = acc[rh][chh][i][2] * zv;
                o.w = acc[rh][chh][i][3] * zv;
                *(float4*)&out[((size_t)(b*Tt + t0 + row)*Hh + h)*Dd + c0 + chh*64 + tx*4] = o;
            }
        }
}

extern "C" void kernel_launch(void* const* d_in, const int* in_sizes, int n_in,
                              void* d_out, int out_size, void* d_ws, size_t ws_size,
                              hipStream_t stream)
{
    const float* x  = (const float*)d_in[0];
    const float* WQ = (const float*)d_in[1];
    const float* WK = (const float*)d_in[2];
    const float* WV = (const float*)d_in[3];
    const float* Wp = (const float*)d_in[4];
    float* ws = (float*)d_ws;
    float* qf     = ws + OFF_QF;
    float* kf     = ws + OFF_KF;
    float* vf     = ws + OFF_V;
    float* kvpart = ws + OFF_KVP;
    float* kspart = ws + OFF_KSP;
    float* kv     = ws + OFF_KV;
    float* ksum   = ws + OFF_KS;
    float* kvq    = ws + OFF_KVQ;
    float* zz     = ws + OFF_Z;
    unsigned short* abig = (unsigned short*)(ws + OFF_AB);
    unsigned short* wqb  = (unsigned short*)(ws + OFF_WQB);
    unsigned short* wkb  = (unsigned short*)(ws + OFF_WKB);
    unsigned short* wvb  = (unsigned short*)(ws + OFF_WVB);
    float* out = (float*)d_out;

    dim3 blk(256);
    // split fp32 -> (hi,lo) bf16 operand buffers
    split_a<<<(BT*1024/4)/256, blk, 0, stream>>>(x, abig);
    split_w<<<(1024*1024/4)/256, blk, 0, stream>>>(WQ, wqb);
    split_w<<<(1024*1024/4)/256, blk, 0, stream>>>(WK, wkb);
    split_w<<<(1024*1024/4)/256, blk, 0, stream>>>(WV, wvb);
    // QKV projections via split-bf16 MFMA (fp32-accurate), feature map fused for Q,K
    gemm_mfma<1><<<dim3(8, 64), blk, 0, stream>>>(abig, wqb, qf);
    gemm_mfma<1><<<dim3(8, 64), blk, 0, stream>>>(abig, wkb, kf);
    gemm_mfma<0><<<dim3(8, 64), blk, 0, stream>>>(abig, wvb, vf);
    // kv & ksum reduction over T
    kv_partial<<<dim3(32, NCH), blk, 0, stream>>>(kf, vf, kvpart, kspart);
    kv_reduce<<<(32*4096 + 32*64 + 255)/256, blk, 0, stream>>>(kvpart, kspart, kv, ksum);
    // fold output projection into kv
    kvp_kernel<<<(32*64*1024)/256, blk, 0, stream>>>(kv, Wp, kvq);
    // normalizer
    z_kernel<<<(BT*Hh)/256, blk, 0, stream>>>(qf, ksum, zz);
    // final: out = z * (q @ kvq)
    final_gemm<<<dim3(8, 32, 32), blk, 0, stream>>>(qf, kvq, zz, out);
}

// Round 3
// 525.487 us; speedup vs baseline: 1.8502x; 1.2011x over previous
//
#include <hip/hip_runtime.h>

#define Bb 2
#define Tt 4096
#define Dd 1024
#define Hh 16
#define QKd 64
#define VDd 64
#define BT (Bb*Tt)          // 8192
#define NCH 16
#define CHUNK (Tt/NCH)      // 256

// workspace layout (float units)
#define OFF_QF  0
#define OFF_KF  (OFF_QF + (size_t)BT*Dd)
#define OFF_V   (OFF_KF + (size_t)BT*Dd)
#define OFF_KVP (OFF_V + (size_t)BT*Dd)          // kv partials: NCH*32*4096
#define OFF_KSP (OFF_KVP + (size_t)NCH*32*4096)  // ksum partials: NCH*32*64
#define OFF_KV  (OFF_KSP + (size_t)NCH*32*64)    // 32*4096
#define OFF_KS  (OFF_KV + (size_t)32*4096)       // 32*64
#define OFF_Z   (OFF_KS + (size_t)32*64)         // BT*Hh
#define OFF_AB  (OFF_Z + (size_t)BT*Hh)          // Abig: BT x 2048 ushort (hi|lo)
#define OFF_WB  (OFF_AB + (size_t)BT*2048/2)     // Wbig: 3072 x 3072 ushort (hi|lo|hi), rows=WQ|WK|WV
#define OFF_KVQB (OFF_WB + (size_t)3072*3072/2)  // kvqb: 32 x 1024 x 192 ushort (hi|lo|hi over d)
#define OFF_QSB (OFF_KVQB + (size_t)32*1024*192/2) // qsb: 32 x 4096 x 128 ushort (hi|lo of z*q)

typedef __attribute__((ext_vector_type(8))) short short8;
typedef __attribute__((ext_vector_type(4))) float f32x4;

__device__ __forceinline__ float featmap(float x) {
    return x > 0.f ? x + 1.f : __expf(x);
}

__device__ __forceinline__ unsigned short bf16_rne(float f) {
    unsigned int u = __float_as_uint(f);
    unsigned int r = u + 0x7fffu + ((u >> 16) & 1u);
    return (unsigned short)(r >> 16);
}
__device__ __forceinline__ float bf16_to_f(unsigned short h) {
    return __uint_as_float(((unsigned int)h) << 16);
}

// split x[8192][1024] f32 -> Abig[8192][2048] bf16: cols [0,1024)=hi, [1024,2048)=lo
__global__ __launch_bounds__(256) void split_a(const float* __restrict__ src,
                                               unsigned short* __restrict__ dst)
{
    int idx = blockIdx.x * 256 + threadIdx.x;
    int m = idx >> 8;
    int c = (idx & 255) << 2;
    float4 v = *(const float4*)&src[(size_t)m * 1024 + c];
    ushort4 hi, lo;
    hi.x = bf16_rne(v.x); lo.x = bf16_rne(v.x - bf16_to_f(hi.x));
    hi.y = bf16_rne(v.y); lo.y = bf16_rne(v.y - bf16_to_f(hi.y));
    hi.z = bf16_rne(v.z); lo.z = bf16_rne(v.z - bf16_to_f(hi.z));
    hi.w = bf16_rne(v.w); lo.w = bf16_rne(v.w - bf16_to_f(hi.w));
    *(ushort4*)&dst[(size_t)m * 2048 + c] = hi;
    *(ushort4*)&dst[(size_t)m * 2048 + 1024 + c] = lo;
}

// split W[1024][1024] f32 -> dst rows [m][3072] bf16: [0,1024)=hi, [1024,2048)=lo, [2048,3072)=hi
__global__ __launch_bounds__(256) void split_w(const float* __restrict__ src,
                                               unsigned short* __restrict__ dst)
{
    int idx = blockIdx.x * 256 + threadIdx.x;
    int m = idx >> 8;
    int c = (idx & 255) << 2;
    float4 v = *(const float4*)&src[(size_t)m * 1024 + c];
    ushort4 hi, lo;
    hi.x = bf16_rne(v.x); lo.x = bf16_rne(v.x - bf16_to_f(hi.x));
    hi.y = bf16_rne(v.y); lo.y = bf16_rne(v.y - bf16_to_f(hi.y));
    hi.z = bf16_rne(v.z); lo.z = bf16_rne(v.z - bf16_to_f(hi.z));
    hi.w = bf16_rne(v.w); lo.w = bf16_rne(v.w - bf16_to_f(hi.w));
    *(ushort4*)&dst[(size_t)m * 3072 + c] = hi;
    *(ushort4*)&dst[(size_t)m * 3072 + 1024 + c] = lo;
    *(ushort4*)&dst[(size_t)m * 3072 + 2048 + c] = hi;
}

#define GLLDS(gp, lp) __builtin_amdgcn_global_load_lds( \
    (const __attribute__((address_space(1))) void*)(gp), \
    (__attribute__((address_space(3))) void*)(lp), 16, 0, 0)

// Combined QKV projection: C[8192][3072] = Abig x Wbig^T over effective K=3072
// (hi*hi + hi*lo + lo*hi = fp32-accurate). Output routed: cols [0,1024)->qf (ELU),
// [1024,2048)->kf (ELU), [2048,3072)->vf. m97 structure: 128x128 tile, 4 waves.
__global__ __launch_bounds__(256) void gemm_qkv(const unsigned short* __restrict__ A,
                                                const unsigned short* __restrict__ W,
                                                float* __restrict__ qf,
                                                float* __restrict__ kf,
                                                float* __restrict__ vf)
{
    __shared__ unsigned short Als[2][128*32];
    __shared__ unsigned short Bls[2][128*32];
    const int tid  = threadIdx.x;
    const int lane = tid & 63;
    const int wave = tid >> 6;
    const int bx = blockIdx.x;
    const int n0 = bx * 128;
    const int m0 = blockIdx.y * 128;
    const int wr = (wave >> 1) * 64;
    const int wc = (wave & 1) * 64;
    f32x4 acc[4][4] = {};

    auto stage = [&](int buf, int kt) {
        const int k0 = kt * 32;
        const int pass = k0 >> 10;
        const int acol = (pass == 2) ? (k0 - 1024) : (k0 & 1023);
        #pragma unroll
        for (int i = 0; i < 2; ++i) {
            int s = i * 256 + tid;
            int row = s >> 2, g = s & 3;
            GLLDS(&A[(size_t)(m0 + row) * 2048 + acol + g * 8], &Als[buf][s * 8]);
            GLLDS(&W[(size_t)(n0 + row) * 3072 + k0   + g * 8], &Bls[buf][s * 8]);
        }
    };

    stage(0, 0);
    const int arow = (lane & 15) * 32 + (lane >> 4) * 8;
    for (int kt = 0; kt < 96; ++kt) {
        const int buf = kt & 1;
        __syncthreads();
        if (kt + 1 < 96) stage(buf ^ 1, kt + 1);
        short8 af[4], bfr[4];
        #pragma unroll
        for (int m = 0; m < 4; ++m)
            af[m] = *(const short8*)&Als[buf][(wr + m*16)*32 + arow];
        #pragma unroll
        for (int n = 0; n < 4; ++n)
            bfr[n] = *(const short8*)&Bls[buf][(wc + n*16)*32 + arow];
        #pragma unroll
        for (int m = 0; m < 4; ++m)
            #pragma unroll
            for (int n = 0; n < 4; ++n)
                acc[m][n] = __builtin_amdgcn_mfma_f32_16x16x32_bf16(af[m], bfr[n], acc[m][n], 0, 0, 0);
    }

    float* Cb = (bx < 8) ? qf : ((bx < 16) ? kf : vf);
    const int elu = (bx < 16);
    const int c0 = n0 & 1023;
    #pragma unroll
    for (int m = 0; m < 4; ++m) {
        #pragma unroll
        for (int n = 0; n < 4; ++n) {
            #pragma unroll
            for (int r = 0; r < 4; ++r) {
                float v = acc[m][n][r];
                if (elu) v = featmap(v);
                int row = m0 + wr + m*16 + ((lane >> 4) << 2) + r;
                int col = c0 + wc + n*16 + (lane & 15);
                Cb[(size_t)row * 1024 + col] = v;
            }
        }
    }
}

// per (b,h), T-chunk: partial kv[64][64] and ksum[64]
__global__ __launch_bounds__(256) void kv_partial(const float* __restrict__ kf,
        const float* __restrict__ vf, float* __restrict__ kvpart, float* __restrict__ kspart)
{
    const int bh = blockIdx.x;
    const int ch = blockIdx.y;
    const int b = bh >> 4, h = bh & 15;
    __shared__ float sk[8][64];
    __shared__ float sv[8][64];
    const int tid = threadIdx.x;
    const int r0 = (tid >> 4) << 2;
    const int c0 = (tid & 15) << 2;
    const int tt = tid >> 5;
    const int rem = tid & 31;
    const int which = rem >> 4;
    const int d4 = (rem & 15) << 2;
    const float* src = which ? vf : kf;
    float acc[4][4] = {};
    float ksl = 0.f;
    for (int t0 = ch * CHUNK; t0 < (ch + 1) * CHUNK; t0 += 8) {
        const int t = t0 + tt;
        float4 val = *(const float4*)&src[(size_t)(b*Tt + t)*Dd + h*QKd + d4];
        __syncthreads();
        if (which) *(float4*)&sv[tt][d4] = val;
        else       *(float4*)&sk[tt][d4] = val;
        __syncthreads();
        #pragma unroll
        for (int s = 0; s < 8; ++s) {
            float4 k4v = *(const float4*)&sk[s][r0];
            float4 v4v = *(const float4*)&sv[s][c0];
            float kvv[4] = {k4v.x,k4v.y,k4v.z,k4v.w};
            float vvv[4] = {v4v.x,v4v.y,v4v.z,v4v.w};
            #pragma unroll
            for (int i = 0; i < 4; ++i)
                #pragma unroll
                for (int j = 0; j < 4; ++j)
                    acc[i][j] = fmaf(kvv[i], vvv[j], acc[i][j]);
        }
        if (tid < 64) {
            #pragma unroll
            for (int s = 0; s < 8; ++s) ksl += sk[s][tid];
        }
    }
    const size_t base = (size_t)(ch*32 + bh) * 4096;
    #pragma unroll
    for (int i = 0; i < 4; ++i) {
        float4 o = {acc[i][0], acc[i][1], acc[i][2], acc[i][3]};
        *(float4*)&kvpart[base + (r0+i)*64 + c0] = o;
    }
    if (tid < 64) kspart[(size_t)(ch*32 + bh)*64 + tid] = ksl;
}

__global__ __launch_bounds__(256) void kv_reduce(const float* __restrict__ kvpart,
        const float* __restrict__ kspart, float* __restrict__ kv, float* __restrict__ ksum)
{
    int g = blockIdx.x * 256 + threadIdx.x;
    if (g < 32*4096) {
        float s = 0.f;
        #pragma unroll
        for (int c = 0; c < NCH; ++c) s += kvpart[(size_t)c*(32*4096) + g];
        kv[g] = s;
    } else if (g < 32*4096 + 32*64) {
        int g2 = g - 32*4096;
        float s = 0.f;
        #pragma unroll
        for (int c = 0; c < NCH; ++c) s += kspart[(size_t)c*(32*64) + g2];
        ksum[g2] = s;
    }
}

// kvqb[bh][c][0..191] bf16 = split of kvq[d][c] = sum_m kv[bh][d][m]*Wproj[c][m]; hi|lo|hi over d
__global__ __launch_bounds__(256) void kvpb_kernel(const float* __restrict__ kv,
        const float* __restrict__ wproj, unsigned short* __restrict__ kvqb)
{
    int flat = blockIdx.x * 256 + threadIdx.x;   // ((bh*1024)+c)*64+d
    int d = flat & 63;
    int c = (flat >> 6) & 1023;
    int bh = flat >> 16;
    const float4* kr = (const float4*)&kv[(size_t)(bh*64 + d)*64];
    const float4* wr = (const float4*)&wproj[(size_t)c*64];
    float s = 0.f;
    #pragma unroll
    for (int m = 0; m < 16; ++m) {
        float4 a = kr[m], bq = wr[m];
        s += a.x*bq.x + a.y*bq.y + a.z*bq.z + a.w*bq.w;
    }
    unsigned short hi = bf16_rne(s);
    unsigned short lo = bf16_rne(s - bf16_to_f(hi));
    size_t base = ((size_t)bh*1024 + c) * 192;
    kvqb[base + d] = hi;
    kvqb[base + 64 + d] = lo;
    kvqb[base + 128 + d] = hi;
}

// z[bt*16+h] = 1 / dot(q[bt,h,:], ksum[b,h,:])
__global__ __launch_bounds__(256) void z_kernel(const float* __restrict__ qf,
        const float* __restrict__ ksum, float* __restrict__ z)
{
    int r = blockIdx.x * 256 + threadIdx.x;
    int bt = r >> 4, h = r & 15;
    int b = bt >> 12;
    const float4* qr = (const float4*)&qf[(size_t)bt*Dd + h*64];
    const float4* kr = (const float4*)&ksum[(size_t)(b*16 + h)*64];
    float s = 0.f;
    #pragma unroll
    for (int m = 0; m < 16; ++m) {
        float4 a = qr[m], bq = kr[m];
        s += a.x*bq.x + a.y*bq.y + a.z*bq.z + a.w*bq.w;
    }
    z[r] = 1.f / s;
}

// qsb[bh][t][0..127] bf16 = split of z[bt,h] * q[bt,h,d]; hi(0-63)|lo(64-127)
__global__ __launch_bounds__(256) void qsplit(const float* __restrict__ qf,
        const float* __restrict__ z, unsigned short* __restrict__ qsb)
{
    int idx = blockIdx.x * 256 + threadIdx.x;   // over BT*1024/4 float4s
    int m = idx >> 8;            // bt
    int c4 = (idx & 255) << 2;   // col in [0,1024)
    int h = c4 >> 6, d = c4 & 63;
    int b = m >> 12, t = m & 4095;
    float zv = z[m*16 + h];
    float4 v = *(const float4*)&qf[(size_t)m * 1024 + c4];
    v.x *= zv; v.y *= zv; v.z *= zv; v.w *= zv;
    ushort4 hi, lo;
    hi.x = bf16_rne(v.x); lo.x = bf16_rne(v.x - bf16_to_f(hi.x));
    hi.y = bf16_rne(v.y); lo.y = bf16_rne(v.y - bf16_to_f(hi.y));
    hi.z = bf16_rne(v.z); lo.z = bf16_rne(v.z - bf16_to_f(hi.z));
    hi.w = bf16_rne(v.w); lo.w = bf16_rne(v.w - bf16_to_f(hi.w));
    size_t base = ((size_t)(b*16 + h)*4096 + t) * 128;
    *(ushort4*)&qsb[base + d] = hi;
    *(ushort4*)&qsb[base + 64 + d] = lo;
}

// out[((b*4096+t)*16+h)*1024 + c] = sum_d zq[bh][t][d] * kvq[bh][d][c], split-bf16 MFMA, K_eff=192
__global__ __launch_bounds__(256) void fgemm(const unsigned short* __restrict__ qsb,
        const unsigned short* __restrict__ kvqb, float* __restrict__ out)
{
    __shared__ unsigned short Als[2][128*32];
    __shared__ unsigned short Bls[2][128*32];
    const int tid  = threadIdx.x;
    const int lane = tid & 63;
    const int wave = tid >> 6;
    const int bh = blockIdx.z;
    const int b = bh >> 4, h = bh & 15;
    const int t0 = blockIdx.y * 128;
    const int c0 = blockIdx.x * 128;
    const int wr = (wave >> 1) * 64;
    const int wc = (wave & 1) * 64;
    f32x4 acc[4][4] = {};

    auto stage = [&](int buf, int kt) {
        const int k0 = kt * 32;
        const int pass = k0 >> 6;
        const int acol = (pass == 2) ? (k0 - 64) : (k0 & 63);
        #pragma unroll
        for (int i = 0; i < 2; ++i) {
            int s = i * 256 + tid;
            int row = s >> 2, g = s & 3;
            GLLDS(&qsb[((size_t)bh*4096 + t0 + row) * 128 + acol + g * 8], &Als[buf][s * 8]);
            GLLDS(&kvqb[((size_t)bh*1024 + c0 + row) * 192 + k0 + g * 8], &Bls[buf][s * 8]);
        }
    };

    stage(0, 0);
    const int arow = (lane & 15) * 32 + (lane >> 4) * 8;
    for (int kt = 0; kt < 6; ++kt) {
        const int buf = kt & 1;
        __syncthreads();
        if (kt + 1 < 6) stage(buf ^ 1, kt + 1);
        short8 af[4], bfr[4];
        #pragma unroll
        for (int m = 0; m < 4; ++m)
            af[m] = *(const short8*)&Als[buf][(wr + m*16)*32 + arow];
        #pragma unroll
        for (int n = 0; n < 4; ++n)
            bfr[n] = *(const short8*)&Bls[buf][(wc + n*16)*32 + arow];
        #pragma unroll
        for (int m = 0; m < 4; ++m)
            #pragma unroll
            for (int n = 0; n < 4; ++n)
                acc[m][n] = __builtin_amdgcn_mfma_f32_16x16x32_bf16(af[m], bfr[n], acc[m][n], 0, 0, 0);
    }

    #pragma unroll
    for (int m = 0; m < 4; ++m) {
        #pragma unroll
        for (int n = 0; n < 4; ++n) {
            #pragma unroll
            for (int r = 0; r < 4; ++r) {
                int trow = t0 + wr + m*16 + ((lane >> 4) << 2) + r;
                int col = c0 + wc + n*16 + (lane & 15);
                out[((size_t)(b*4096 + trow)*16 + h)*1024 + col] = acc[m][n][r];
            }
        }
    }
}

extern "C" void kernel_launch(void* const* d_in, const int* in_sizes, int n_in,
                              void* d_out, int out_size, void* d_ws, size_t ws_size,
                              hipStream_t stream)
{
    const float* x  = (const float*)d_in[0];
    const float* WQ = (const float*)d_in[1];
    const float* WK = (const float*)d_in[2];
    const float* WV = (const float*)d_in[3];
    const float* Wp = (const float*)d_in[4];
    float* ws = (float*)d_ws;
    float* qf     = ws + OFF_QF;
    float* kf     = ws + OFF_KF;
    float* vf     = ws + OFF_V;
    float* kvpart = ws + OFF_KVP;
    float* kspart = ws + OFF_KSP;
    float* kv     = ws + OFF_KV;
    float* ksum   = ws + OFF_KS;
    float* zz     = ws + OFF_Z;
    unsigned short* abig = (unsigned short*)(ws + OFF_AB);
    unsigned short* wb   = (unsigned short*)(ws + OFF_WB);
    unsigned short* kvqb = (unsigned short*)(ws + OFF_KVQB);
    unsigned short* qsb  = (unsigned short*)(ws + OFF_QSB);
    float* out = (float*)d_out;

    dim3 blk(256);
    // split fp32 -> (hi,lo) bf16 operand buffers
    split_a<<<(BT*1024/4)/256, blk, 0, stream>>>(x, abig);
    split_w<<<(1024*1024/4)/256, blk, 0, stream>>>(WQ, wb);
    split_w<<<(1024*1024/4)/256, blk, 0, stream>>>(WK, wb + (size_t)1024*3072);
    split_w<<<(1024*1024/4)/256, blk, 0, stream>>>(WV, wb + (size_t)2048*3072);
    // combined QKV projection (fp32-accurate split MFMA), ELU fused for Q,K
    gemm_qkv<<<dim3(24, 64), blk, 0, stream>>>(abig, wb, qf, kf, vf);
    // kv & ksum reduction over T
    kv_partial<<<dim3(32, NCH), blk, 0, stream>>>(kf, vf, kvpart, kspart);
    kv_reduce<<<(32*4096 + 32*64 + 255)/256, blk, 0, stream>>>(kvpart, kspart, kv, ksum);
    // normalizer
    z_kernel<<<(BT*Hh)/256, blk, 0, stream>>>(qf, ksum, zz);
    // fold output projection into kv, split to bf16
    kvpb_kernel<<<(32*1024*64)/256, blk, 0, stream>>>(kv, Wp, kvqb);
    // z-scaled q, split to bf16
    qsplit<<<(BT*1024/4)/256, blk, 0, stream>>>(qf, zz, qsb);
    // final: out = (z*q) @ kvq via split MFMA
    fgemm<<<dim3(8, 32, 32), blk, 0, stream>>>(qsb, kvqb, out);
}